// Round 1
// baseline (69.304 us; speedup 1.0000x reference)
//
#include <hip/hip_runtime.h>

// Problem constants (from reference): logits [8,19,512,1024] f32,
// labels [8,512,1024] i32, smooth_labels unused. Output: scalar mean NLL.
#define BB   8
#define CC   19
#define HH   512
#define WW   1024
#define HWSZ (HH * WW)                     // 524288
#define NPIX ((long long)BB * HWSZ)        // 4194304
#define BLOCK 256
#define PIX_PER_THREAD 4
#define NQUAD (NPIX / PIX_PER_THREAD)      // 1048576
#define GRID  ((int)(NQUAD / BLOCK))       // 4096 blocks

__global__ __launch_bounds__(BLOCK) void ce_partial_kernel(
        const float* __restrict__ logits,
        const int*   __restrict__ labels,
        float*       __restrict__ partial) {
    // quad index -> 4 consecutive pixels (never crosses batch boundary:
    // HWSZ % 4 == 0)
    long long q = (long long)blockIdx.x * BLOCK + threadIdx.x;
    long long p = q * PIX_PER_THREAD;
    int b  = (int)(p / HWSZ);
    int hw = (int)(p - (long long)b * HWSZ);
    const float* base = logits + (long long)b * CC * HWSZ + hw;

    // Load all 19 class planes as float4 (16B/lane, fully coalesced per plane)
    float a[PIX_PER_THREAD][CC];
#pragma unroll
    for (int c = 0; c < CC; ++c) {
        float4 t = *reinterpret_cast<const float4*>(base + (long long)c * HWSZ);
        a[0][c] = t.x; a[1][c] = t.y; a[2][c] = t.z; a[3][c] = t.w;
    }
    int4 lab4 = *reinterpret_cast<const int4*>(labels + p);
    int labv[PIX_PER_THREAD] = { lab4.x, lab4.y, lab4.z, lab4.w };

    float local = 0.0f;
#pragma unroll
    for (int j = 0; j < PIX_PER_THREAD; ++j) {
        float m = a[j][0];
#pragma unroll
        for (int c = 1; c < CC; ++c) m = fmaxf(m, a[j][c]);
        float s = 0.0f;
        float pick = 0.0f;   // in-register gather: select chain, no scratch
#pragma unroll
        for (int c = 0; c < CC; ++c) {
            s += __expf(a[j][c] - m);
            pick = (labv[j] == c) ? a[j][c] : pick;
        }
        float nll = m + __logf(s) - pick;
        // ignore_index = -1: contributes 0 to numerator, still in denominator
        local += (labv[j] != -1) ? nll : 0.0f;
    }

    // wave (64-lane) shuffle reduction
#pragma unroll
    for (int off = 32; off > 0; off >>= 1)
        local += __shfl_down(local, off);

    __shared__ float smem[BLOCK / 64];
    int wave = threadIdx.x >> 6;
    int lane = threadIdx.x & 63;
    if (lane == 0) smem[wave] = local;
    __syncthreads();
    if (threadIdx.x == 0) {
        float bs = 0.0f;
#pragma unroll
        for (int w = 0; w < BLOCK / 64; ++w) bs += smem[w];
        partial[blockIdx.x] = bs;
    }
}

__global__ __launch_bounds__(256) void ce_final_kernel(
        const float* __restrict__ partial,
        float*       __restrict__ out) {
    // deterministic single-block finish; double accumulation for the
    // 4096-partial sum (total ~1.26e7, keep precision comfortable)
    double s = 0.0;
    for (int i = threadIdx.x; i < GRID; i += 256)
        s += (double)partial[i];
#pragma unroll
    for (int off = 32; off > 0; off >>= 1)
        s += __shfl_down(s, off);

    __shared__ double smem[4];
    int wave = threadIdx.x >> 6;
    int lane = threadIdx.x & 63;
    if (lane == 0) smem[wave] = s;
    __syncthreads();
    if (threadIdx.x == 0) {
        double tot = smem[0] + smem[1] + smem[2] + smem[3];
        out[0] = (float)(tot / (double)NPIX);
    }
}

extern "C" void kernel_launch(void* const* d_in, const int* in_sizes, int n_in,
                              void* d_out, int out_size, void* d_ws, size_t ws_size,
                              hipStream_t stream) {
    const float* logits = (const float*)d_in[0];
    const int*   labels = (const int*)d_in[1];
    // d_in[2] = smooth_labels: dead in the reference (OHEM branch discarded).
    float* out     = (float*)d_out;
    float* partial = (float*)d_ws;   // needs GRID*4 = 16 KiB of workspace

    ce_partial_kernel<<<GRID, BLOCK, 0, stream>>>(logits, labels, partial);
    ce_final_kernel<<<1, 256, 0, stream>>>(partial, out);
}

// Round 3
// 57.906 us; speedup vs baseline: 1.1968x; 1.1968x over previous
//
#include <hip/hip_runtime.h>

// logits [8,19,512,1024] f32, labels [8,512,1024] i32, smooth_labels unused
// (OHEM branch discarded in reference). Output: scalar mean NLL over all
// pixels (ignored pixels contribute 0 to numerator, count in denominator).
#define CC    19
#define HWSH  19                            // log2(512*1024)
#define HWSZ  (512 * 1024)
#define NPIX  (8LL * HWSZ)                  // 4194304
#define BLOCK 256
#define PPT   4
#define GRID  ((int)(NPIX / PPT / BLOCK))   // 4096 blocks

// clang native vectors — accepted by __builtin_nontemporal_load
typedef float f32x4 __attribute__((ext_vector_type(4)));
typedef int   i32x4 __attribute__((ext_vector_type(4)));

__device__ __forceinline__ f32x4 ntload_f4(const float* p) {
    return __builtin_nontemporal_load(reinterpret_cast<const f32x4*>(p));
}
__device__ __forceinline__ i32x4 ntload_i4(const int* p) {
    return __builtin_nontemporal_load(reinterpret_cast<const i32x4*>(p));
}

// Online-softmax over one chunk of classes already resident in registers.
// All indices compile-time (full unroll) -> stays in VGPRs.
template <int N>
__device__ __forceinline__ void chunk_reduce(const float (&a)[N], int lab,
                                             int c0, float& m, float& s,
                                             float& pick) {
    m = a[0];
#pragma unroll
    for (int c = 1; c < N; ++c) m = fmaxf(m, a[c]);
    s = 0.0f;
#pragma unroll
    for (int c = 0; c < N; ++c) {
        s += __expf(a[c] - m);
        pick = (lab == c0 + c) ? a[c] : pick;
    }
}

__global__ __launch_bounds__(BLOCK) void ce_partial_kernel(
        const float* __restrict__ logits,
        const int*   __restrict__ labels,
        float*       __restrict__ partial) {
    long long q = (long long)blockIdx.x * BLOCK + threadIdx.x;
    long long p = q * PPT;                       // 4 consecutive pixels
    int b  = (int)(p >> HWSH);
    int hw = (int)(p & (HWSZ - 1));
    const float* base = logits + ((long long)b * CC << HWSH) + hw;

    i32x4 lab4 = ntload_i4(labels + p);
    int labv[PPT] = { lab4.x, lab4.y, lab4.z, lab4.w };

    float local = 0.0f;

    // ---- chunk 0: classes 0..9 (peak live: 40 floats) ----
    float m1[PPT], s1[PPT], pick[PPT] = {0, 0, 0, 0};
    {
        float a0[10], a1[10], a2[10], a3[10];
#pragma unroll
        for (int c = 0; c < 10; ++c) {
            f32x4 t = ntload_f4(base + ((long long)c << HWSH));
            a0[c] = t.x; a1[c] = t.y; a2[c] = t.z; a3[c] = t.w;
        }
        chunk_reduce(a0, labv[0], 0, m1[0], s1[0], pick[0]);
        chunk_reduce(a1, labv[1], 0, m1[1], s1[1], pick[1]);
        chunk_reduce(a2, labv[2], 0, m1[2], s1[2], pick[2]);
        chunk_reduce(a3, labv[3], 0, m1[3], s1[3], pick[3]);
    }

    // ---- chunk 1: classes 10..18, then online combine ----
    {
        float a0[9], a1[9], a2[9], a3[9];
#pragma unroll
        for (int c = 0; c < 9; ++c) {
            f32x4 t = ntload_f4(base + ((long long)(c + 10) << HWSH));
            a0[c] = t.x; a1[c] = t.y; a2[c] = t.z; a3[c] = t.w;
        }
        float m2[PPT], s2[PPT];
        chunk_reduce(a0, labv[0], 10, m2[0], s2[0], pick[0]);
        chunk_reduce(a1, labv[1], 10, m2[1], s2[1], pick[1]);
        chunk_reduce(a2, labv[2], 10, m2[2], s2[2], pick[2]);
        chunk_reduce(a3, labv[3], 10, m2[3], s2[3], pick[3]);

#pragma unroll
        for (int j = 0; j < PPT; ++j) {
            float mm = fmaxf(m1[j], m2[j]);
            float ss = s1[j] * __expf(m1[j] - mm) + s2[j] * __expf(m2[j] - mm);
            float nll = mm + __logf(ss) - pick[j];
            local += (labv[j] != -1) ? nll : 0.0f;
        }
    }

    // wave (64) shuffle reduce -> per-block partial
#pragma unroll
    for (int off = 32; off > 0; off >>= 1)
        local += __shfl_down(local, off);

    __shared__ float smem[BLOCK / 64];
    if ((threadIdx.x & 63) == 0) smem[threadIdx.x >> 6] = local;
    __syncthreads();
    if (threadIdx.x == 0) {
        float bs = 0.0f;
#pragma unroll
        for (int w = 0; w < BLOCK / 64; ++w) bs += smem[w];
        partial[blockIdx.x] = bs;
    }
}

__global__ __launch_bounds__(1024) void ce_final_kernel(
        const float* __restrict__ partial,
        float*       __restrict__ out) {
    // 4096 partials = 1024 threads x float4; deterministic fixed-order sum
    f32x4 v = *reinterpret_cast<const f32x4*>(partial + threadIdx.x * 4);
    double s = (double)v.x + (double)v.y + (double)v.z + (double)v.w;
#pragma unroll
    for (int off = 32; off > 0; off >>= 1)
        s += __shfl_down(s, off);

    __shared__ double smem[16];
    if ((threadIdx.x & 63) == 0) smem[threadIdx.x >> 6] = s;
    __syncthreads();
    if (threadIdx.x == 0) {
        double tot = 0.0;
#pragma unroll
        for (int w = 0; w < 16; ++w) tot += smem[w];
        out[0] = (float)(tot / (double)NPIX);
    }
}

extern "C" void kernel_launch(void* const* d_in, const int* in_sizes, int n_in,
                              void* d_out, int out_size, void* d_ws, size_t ws_size,
                              hipStream_t stream) {
    const float* logits = (const float*)d_in[0];
    const int*   labels = (const int*)d_in[1];
    // d_in[2] = smooth_labels: dead (reference discards the OHEM branch).
    float* out     = (float*)d_out;
    float* partial = (float*)d_ws;   // GRID*4 = 16 KiB scratch

    ce_partial_kernel<<<GRID, BLOCK, 0, stream>>>(logits, labels, partial);
    ce_final_kernel<<<1, 1024, 0, stream>>>(partial, out);
}